// Round 15
// baseline (451.856 us; speedup 1.0000x reference)
//
#include <hip/hip_runtime.h>
#include <math.h>

#define BB 4
#define NN 256
#define DD 512
#define HH 8
#define LL 6
#define TDIM 128
#define KNN 16
#define KEE 4
#define DHH 64
#define PSTRIDE ((size_t)BB * NN * NN * KEE)

typedef unsigned short u16;
typedef __bf16 bf16x8 __attribute__((ext_vector_type(8)));
typedef float f32x16 __attribute__((ext_vector_type(16)));
typedef u16 u16x8 __attribute__((ext_vector_type(8)));
typedef u16 u16x4 __attribute__((ext_vector_type(4)));
typedef unsigned int u32;

#define GLOBAL_AS(p) ((__attribute__((address_space(1))) void*)(p))
#define LDS_AS(p)    ((__attribute__((address_space(3))) void*)(p))

__device__ __forceinline__ u16 f2bf(float x) {
    unsigned u = __float_as_uint(x);
    u = (u + 0x7FFFu + ((u >> 16) & 1u)) >> 16;
    return (u16)u;
}
__device__ __forceinline__ float bf2f(u16 x) {
    return __uint_as_float(((unsigned)x) << 16);
}
__device__ __forceinline__ u32 cvtpk_bf16(float lo, float hi) {
    u32 r;
    asm("v_cvt_pk_bf16_f32 %0, %1, %2" : "=v"(r) : "v"(lo), "v"(hi));
    return r;
}

// ---------------- time embedding ----------------
__global__ void temb_kernel(const int* __restrict__ t_in, const float* __restrict__ w1,
                            const float* __restrict__ b1, const float* __restrict__ w2,
                            const float* __restrict__ b2, float* __restrict__ temb)
{
    int b = blockIdx.x;
    int t = threadIdx.x; // 512
    __shared__ float t0[TDIM];
    __shared__ float t1[DD];
    float tv = (float)t_in[b];
    if (t < TDIM) {
        int j = t & 63;
        float fr = expf(-logf(10000.f) * (float)j / 64.f);
        float ang = tv * fr;
        t0[t] = (t < 64) ? sinf(ang) : cosf(ang);
    }
    __syncthreads();
    float acc = b1[t];
    for (int k = 0; k < TDIM; ++k) acc += t0[k] * w1[k * DD + t];
    t1[t] = acc / (1.f + expf(-acc));
    __syncthreads();
    float acc2 = b2[t];
    for (int k = 0; k < DD; ++k) acc2 += t1[k] * w2[k * DD + t];
    temb[b * DD + t] = acc2;
}

// ---------------- h init: fp32 + bf16 dual store + row stats (slot 0) ----------------
__global__ __launch_bounds__(256) void inith_kernel(
    const int* __restrict__ xn, const float* __restrict__ ne,
    const float* __restrict__ temb, const float* __restrict__ cemb,
    float* __restrict__ h, u16* __restrict__ hbf, float* __restrict__ statH)
{
    int row = blockIdx.x;          // b*N+n
    int b = row >> 8;
    int t = threadIdx.x;
    int node = xn[row];
    float v0 = ne[(size_t)node * DD + t]       + temb[b * DD + t]       + cemb[b * DD + t];
    float v1 = ne[(size_t)node * DD + t + 256] + temb[b * DD + t + 256] + cemb[b * DD + t + 256];
    h[(size_t)row * DD + t] = v0;
    h[(size_t)row * DD + t + 256] = v1;
    hbf[(size_t)row * DD + t] = f2bf(v0);
    hbf[(size_t)row * DD + t + 256] = f2bf(v1);

    float s = v0 + v1, q = v0 * v0 + v1 * v1;
    #pragma unroll
    for (int o = 32; o; o >>= 1) { s += __shfl_down(s, o); q += __shfl_down(q, o); }
    __shared__ float ps[4][2];
    int w = t >> 6, lane = t & 63;
    if (!lane) { ps[w][0] = s; ps[w][1] = q; }
    __syncthreads();
    if (t == 0) {
        statH[(size_t)row * 32 + 0] = ps[0][0] + ps[1][0] + ps[2][0] + ps[3][0];
        statH[(size_t)row * 32 + 1] = ps[0][1] + ps[1][1] + ps[2][1] + ps[3][1];
    }
    if (t >= 2 && t < 32) statH[(size_t)row * 32 + t] = 0.f;
}

// ---------------- merged weight convert+transpose + LN fold (gamma into W, u/v vectors) ----------------
struct CvtSeg { const float* src; u16* dst; const float* g; const float* b;
                float* u; float* v; int K, N, tx, ty, nl, base; };
struct CvtTab { CvtSeg s[8]; };

__global__ __launch_bounds__(256) void convert_all(CvtTab tab)
{
    const int tile = blockIdx.x;
    int si = 0;
    #pragma unroll
    for (int s2 = 1; s2 < 8; ++s2) if (tile >= tab.s[s2].base) si = s2;
    const CvtSeg sg = tab.s[si];
    int local = tile - sg.base;
    int per = sg.tx * sg.ty;
    int lay = local / per;
    int rem = local - lay * per;
    int bx = rem % sg.tx, by = rem / sg.tx;
    const int kb = by * 64, nb = bx * 64;
    const size_t zoff = (size_t)lay * sg.K * sg.N;
    const int K = sg.K, N = sg.N;

    __shared__ float s[64][65];
    __shared__ float redu[4][64];
    __shared__ float redv[4][64];
    int t = threadIdx.x;
    int r0 = t >> 4, c0 = (t & 15) * 4;
    #pragma unroll
    for (int i = 0; i < 4; ++i) {
        int row = i * 16 + r0;
        float4 v = *reinterpret_cast<const float4*>(sg.src + zoff + (size_t)(kb + row) * N + nb + c0);
        s[row][c0] = v.x; s[row][c0 + 1] = v.y; s[row][c0 + 2] = v.z; s[row][c0 + 3] = v.w;
    }
    __syncthreads();

    if (sg.g) {
        const float* gp = sg.g + lay * DD + kb;
        const float* bp = sg.b + lay * DD + kb;
        #pragma unroll
        for (int i = 0; i < 4; ++i) {
            int n = i * 16 + r0;
            ushort4 o;
            o.x = f2bf(s[c0 + 0][n] * gp[c0 + 0]); o.y = f2bf(s[c0 + 1][n] * gp[c0 + 1]);
            o.z = f2bf(s[c0 + 2][n] * gp[c0 + 2]); o.w = f2bf(s[c0 + 3][n] * gp[c0 + 3]);
            *reinterpret_cast<ushort4*>(sg.dst + zoff + (size_t)(nb + n) * K + kb + c0) = o;
        }
        int col = t & 63, seg = t >> 6;
        float us = 0.f, vs = 0.f;
        #pragma unroll
        for (int r = 0; r < 16; ++r) {
            int row = seg * 16 + r;
            float w_ = s[row][col];
            us += gp[row] * w_;
            vs += bp[row] * w_;
        }
        redu[seg][col] = us;
        redv[seg][col] = vs;
        __syncthreads();
        if (seg == 0) {
            float ut = redu[0][col] + redu[1][col] + redu[2][col] + redu[3][col];
            float vt = redv[0][col] + redv[1][col] + redv[2][col] + redv[3][col];
            atomicAdd(sg.u + (size_t)lay * N + nb + col, ut);
            atomicAdd(sg.v + (size_t)lay * N + nb + col, vt);
        }
    } else {
        #pragma unroll
        for (int i = 0; i < 4; ++i) {
            int n = i * 16 + r0;
            ushort4 o;
            o.x = f2bf(s[c0 + 0][n]); o.y = f2bf(s[c0 + 1][n]);
            o.z = f2bf(s[c0 + 2][n]); o.w = f2bf(s[c0 + 3][n]);
            *reinterpret_cast<ushort4*>(sg.dst + zoff + (size_t)(nb + n) * K + kb + c0) = o;
        }
    }
}

// ---------------- MFMA GEMM, split-K, dbuf ----------------
// MODE 0: plain A bf16. MODE 1: LN-folded — A = raw hbf, gamma pre-folded into B,
// stats from statIn (producer-emitted partials), epilogue val = rs*(acc - m*u[col]) + v[col].
// STAT: epilogue emits per-row (sum,sumsq) partials of the fp32 output into statOut.
template<int WM, int WN, int NR, int KS, int MODE, bool BIAS, bool SILU, bool RES, bool OBF,
         bool HBF, bool STAT>
__global__ __launch_bounds__(WM * WN * 64 * KS) void gemm_mfma(
    const u16* __restrict__ A,
    const u16* __restrict__ B0, const u16* __restrict__ B1, const u16* __restrict__ B2,
    const float* __restrict__ u0, const float* __restrict__ u1, const float* __restrict__ u2,
    const float* __restrict__ v0, const float* __restrict__ v1, const float* __restrict__ v2,
    const float* __restrict__ statIn,
    const float* __restrict__ bias, const float* res,
    void* O0, void* O1, void* O2, u16* hbf, float* statOut,
    int M, int N, int K)
{
    constexpr int BM = WM * 32, BN = WN * NR * 32;
    constexpr int GW = WM * WN;
    constexpr int TH = GW * 64;
    constexpr int ABYTES = BM * 128;
    constexpr int BBYTES = BN * 128;
    constexpr int A16 = ABYTES / 16;
    constexpr int B16 = BBYTES / 16;
    __shared__ char smem[KS * 2 * (ABYTES + BBYTES)];
    __shared__ float statS[MODE == 1 ? BM : 1][2];

    const u16* Bm = B0; void* O = O0;
    const float* Uv = u0; const float* Vv = v0;
    if (blockIdx.z == 1) { Bm = B1; O = O1; Uv = u1; Vv = v1; }
    else if (blockIdx.z == 2) { Bm = B2; O = O2; Uv = u2; Vv = v2; }

    const int t = threadIdx.x;
    const int l = t & 63;
    const int w = t >> 6;
    const int ks = w / GW;
    const int wsub = w - ks * GW;
    const int tl = wsub * 64 + l;
    const int lo = l & 31, hi = l >> 5;
    const int wm = wsub / WN, wn = wsub % WN;
    const int row0 = blockIdx.y * BM;
    const int col0 = blockIdx.x * BN;
    const int NK = K >> 6;
    const int NKh = NK / KS;

    if constexpr (MODE == 1) {
        if (t < BM) {
            const float* sp = statIn + (size_t)(row0 + t) * 32;
            float s = 0.f, q = 0.f;
            #pragma unroll
            for (int i = 0; i < 16; ++i) { s += sp[i * 2]; q += sp[i * 2 + 1]; }
            float m = s / (float)K;
            float var = q / (float)K - m * m;
            statS[t][0] = m;
            statS[t][1] = rsqrtf(var + 1e-5f);
        }
    }

    char* gbase = smem + ks * 2 * (ABYTES + BBYTES);

    int aoff[4];
    int boff[NR][4];
    #pragma unroll
    for (int kc = 0; kc < 4; ++kc) {
        int slot = (kc * 2 + hi) ^ (lo & 7);
        aoff[kc] = (wm * 32 + lo) * 128 + slot * 16;
        #pragma unroll
        for (int nr = 0; nr < NR; ++nr)
            boff[nr][kc] = (wn * NR * 32 + nr * 32 + lo) * 128 + slot * 16;
    }

    auto stage = [&](int buf, int kt) {
        const int k0 = kt * 64;
        char* base = gbase + buf * (ABYTES + BBYTES);
        #pragma unroll
        for (int idx = tl; idx < A16; idx += TH) {
            int r = idx >> 3, s = idx & 7;
            int ss = s ^ (r & 7);
            const u16* g = A + (size_t)(row0 + r) * K + k0 + ss * 8;
            __builtin_amdgcn_global_load_lds(GLOBAL_AS(g), LDS_AS(base + (idx - l) * 16), 16, 0, 0);
        }
        #pragma unroll
        for (int idx = tl; idx < B16; idx += TH) {
            int r = idx >> 3, s = idx & 7;
            int ss = s ^ (r & 7);
            const u16* g = Bm + (size_t)(col0 + r) * K + k0 + ss * 8;
            __builtin_amdgcn_global_load_lds(GLOBAL_AS(g), LDS_AS(base + ABYTES + (idx - l) * 16), 16, 0, 0);
        }
    };

    f32x16 acc[NR];
    #pragma unroll
    for (int nr = 0; nr < NR; ++nr)
        #pragma unroll
        for (int i = 0; i < 16; ++i) acc[nr][i] = 0.f;

    stage(0, ks * NKh);
    __syncthreads();
    int cur = 0;
    for (int kk = 0; kk < NKh; ++kk) {
        if (kk + 1 < NKh) stage(cur ^ 1, ks * NKh + kk + 1);
        const char* base = gbase + cur * (ABYTES + BBYTES);
        #pragma unroll
        for (int kc = 0; kc < 4; ++kc) {
            bf16x8 av = *reinterpret_cast<const bf16x8*>(base + aoff[kc]);
            #pragma unroll
            for (int nr = 0; nr < NR; ++nr) {
                bf16x8 bb = *reinterpret_cast<const bf16x8*>(base + ABYTES + boff[nr][kc]);
                acc[nr] = __builtin_amdgcn_mfma_f32_32x32x16_bf16(av, bb, acc[nr], 0, 0, 0);
            }
        }
        __syncthreads();
        cur ^= 1;
    }

    if (KS > 1) {
        float* exch = (float*)smem;
        if (ks > 0) {
            #pragma unroll
            for (int nr = 0; nr < NR; ++nr)
                #pragma unroll
                for (int r = 0; r < 16; ++r)
                    exch[(((ks - 1) * NR + nr) * 16 + r) * TH + tl] = acc[nr][r];
        }
        __syncthreads();
        if (ks != 0) return;
        #pragma unroll
        for (int g2 = 1; g2 < KS; ++g2)
            #pragma unroll
            for (int nr = 0; nr < NR; ++nr)
                #pragma unroll
                for (int r = 0; r < 16; ++r)
                    acc[nr][r] += exch[(((g2 - 1) * NR + nr) * 16 + r) * TH + tl];
    }

    float v16[STAT ? 16 : 1];

    #pragma unroll
    for (int nr = 0; nr < NR; ++nr) {
        int col = col0 + wn * NR * 32 + nr * 32 + lo;
        float bs = BIAS ? bias[col] : 0.f;
        float uu = 0.f, vvv = 0.f;
        if constexpr (MODE == 1) { uu = Uv[col]; vvv = Vv[col]; }
        #pragma unroll
        for (int r = 0; r < 16; ++r) {
            int lr = wm * 32 + (r & 3) + 8 * (r >> 2) + 4 * hi;
            int row = row0 + lr;
            float val = acc[nr][r];
            if constexpr (MODE == 1)
                val = statS[lr][1] * (val - statS[lr][0] * uu) + vvv;
            val += bs;
            if (SILU) val = val / (1.f + __expf(-val));
            size_t o = (size_t)row * N + col;
            if (RES) val += res[o];
            if (OBF) ((u16*)O)[o] = f2bf(val);
            else { ((float*)O)[o] = val; if (HBF) hbf[o] = f2bf(val); }
            if constexpr (STAT) v16[r] = val;
        }
    }

    if constexpr (STAT) {
        #pragma unroll
        for (int r = 0; r < 16; ++r) {
            float s = v16[r];
            float q = s * s;
            #pragma unroll
            for (int o2 = 1; o2 < 32; o2 <<= 1) { s += __shfl_xor(s, o2); q += __shfl_xor(q, o2); }
            if (lo == 0) {
                int row = row0 + wm * 32 + (r & 3) + 8 * (r >> 2) + 4 * hi;
                int slot = blockIdx.x * 2 + wn;
                statOut[(size_t)row * 32 + slot * 2 + 0] = s;
                statOut[(size_t)row * 32 + slot * 2 + 1] = q;
            }
        }
    }
}

// ---------------- attention v4: full MFMA (S^T = K@Q^T, in-reg softmax, P@V) ----------------
__global__ __launch_bounds__(256) void attn_kernel(
    const u16* __restrict__ q8, const u16* __restrict__ k8, const u16* __restrict__ v8,
    const int* __restrict__ xe, const float* __restrict__ tab, u16* __restrict__ o)
{
    const int qt = blockIdx.x * 32, hh = blockIdx.y, b = blockIdx.z;
    const int t = threadIdx.x;
    const int l = t & 63, w = t >> 6;
    const int lo = l & 31, hi = l >> 5;

    __shared__ u16 Ks[NN * 64];
    __shared__ u16 Qs[32 * 64];
    __shared__ u16 Vt[64 * NN];
    __shared__ float opart[4][32 * 64];
    __shared__ float sums[4][32];
    __shared__ float tabs[KEE * HH];

    #pragma unroll
    for (int c = 0; c < 8; ++c) {
        int idx = c * 256 + t;
        int r = idx >> 3, s = idx & 7;
        int ss = s ^ (r & 7);
        const u16* g = k8 + ((size_t)(b * NN + r) * HH + hh) * DHH + ss * 8;
        __builtin_amdgcn_global_load_lds(GLOBAL_AS(g), LDS_AS((char*)Ks + (idx - l) * 16), 16, 0, 0);
    }
    {
        int r = t >> 3, s = t & 7;
        int ss = s ^ (r & 7);
        const u16* g = q8 + ((size_t)(b * NN + qt + r) * HH + hh) * DHH + ss * 8;
        __builtin_amdgcn_global_load_lds(GLOBAL_AS(g), LDS_AS((char*)Qs + (t - l) * 16), 16, 0, 0);
    }
    if (t < KEE * HH) tabs[t] = tab[t];

    {
        const int d0 = (t & 7) * 8, k0 = (t >> 3) * 8;
        u16x8 va[8];
        #pragma unroll
        for (int i = 0; i < 8; ++i)
            va[i] = *reinterpret_cast<const u16x8*>(v8 + ((size_t)(b * NN + k0 + i) * HH + hh) * DHH + d0);
        #pragma unroll
        for (int j = 0; j < 8; ++j) {
            u16x8 tj;
            #pragma unroll
            for (int i = 0; i < 8; ++i) tj[i] = va[i][j];
            int d = d0 + j;
            int slot = (k0 >> 3) ^ (d & 31);
            *reinterpret_cast<u16x8*>(&Vt[d * 256 + slot * 8]) = tj;
        }
    }
    __syncthreads();

    f32x16 acc[2];
    #pragma unroll
    for (int i = 0; i < 2; ++i)
        #pragma unroll
        for (int r = 0; r < 16; ++r) acc[i][r] = 0.f;

    #pragma unroll
    for (int kc = 0; kc < 4; ++kc) {
        int qslot = (kc * 2 + hi) ^ (lo & 7);
        bf16x8 bq = *reinterpret_cast<const bf16x8*>((char*)Qs + lo * 128 + qslot * 16);
        #pragma unroll
        for (int ktl = 0; ktl < 2; ++ktl) {
            int key = (2 * w + ktl) * 32 + lo;
            int kslot = (kc * 2 + hi) ^ (key & 7);
            bf16x8 ak = *reinterpret_cast<const bf16x8*>((char*)Ks + key * 128 + kslot * 16);
            acc[ktl] = __builtin_amdgcn_mfma_f32_32x32x16_bf16(ak, bq, acc[ktl], 0, 0, 0);
        }
    }

    const int qrow = qt + lo;
    const int* xerow = xe + (size_t)(b * NN + qrow) * NN;
    float psum = 0.f;
    #pragma unroll
    for (int ktl = 0; ktl < 2; ++ktl) {
        #pragma unroll
        for (int r = 0; r < 16; ++r) {
            int key = w * 64 + ktl * 32 + (r & 3) + 8 * (r >> 2) + 4 * hi;
            int e = xerow[key];
            float p = __expf(acc[ktl][r] * 0.125f + tabs[e * HH + hh]);
            acc[ktl][r] = p;
            psum += p;
        }
    }
    psum += __shfl_xor(psum, 32);
    if (hi == 0) sums[w][lo] = psum;

    f32x16 oacc[2];
    #pragma unroll
    for (int i = 0; i < 2; ++i)
        #pragma unroll
        for (int r = 0; r < 16; ++r) oacc[i][r] = 0.f;

    #pragma unroll
    for (int kc = 0; kc < 4; ++kc) {
        const int ai = kc >> 1;
        const int s0 = 8 * (kc & 1);
        u32 W0p = cvtpk_bf16(acc[ai][s0 + 0], acc[ai][s0 + 1]);
        u32 W1p = cvtpk_bf16(acc[ai][s0 + 2], acc[ai][s0 + 3]);
        u32 X0p = cvtpk_bf16(acc[ai][s0 + 4], acc[ai][s0 + 5]);
        u32 X1p = cvtpk_bf16(acc[ai][s0 + 6], acc[ai][s0 + 7]);
        u32 z0 = hi ? W0p : X0p;
        u32 z1 = hi ? W1p : X1p;
        u32 r0 = __shfl_xor((int)z0, 32);
        u32 r1 = __shfl_xor((int)z1, 32);
        u32 F[4];
        F[0] = hi ? r0 : W0p;
        F[1] = hi ? r1 : W1p;
        F[2] = hi ? X0p : r0;
        F[3] = hi ? X1p : r1;
        bf16x8 pf = *reinterpret_cast<const bf16x8*>(F);
        #pragma unroll
        for (int nt = 0; nt < 2; ++nt) {
            int d = nt * 32 + lo;
            int slot = (8 * w + kc * 2 + hi) ^ (d & 31);
            bf16x8 vf = *reinterpret_cast<const bf16x8*>(&Vt[d * 256 + slot * 8]);
            oacc[nt] = __builtin_amdgcn_mfma_f32_32x32x16_bf16(pf, vf, oacc[nt], 0, 0, 0);
        }
    }

    #pragma unroll
    for (int nt = 0; nt < 2; ++nt)
        #pragma unroll
        for (int r = 0; r < 16; ++r) {
            int q = (r & 3) + 8 * (r >> 2) + 4 * hi;
            opart[w][q * 64 + nt * 32 + lo] = oacc[nt][r];
        }
    __syncthreads();

    {
        const int q = t >> 3, dd0 = (t & 7) * 8;
        float denom = sums[0][q] + sums[1][q] + sums[2][q] + sums[3][q];
        float rc = __builtin_amdgcn_rcpf(denom);
        u16x8 o8;
        #pragma unroll
        for (int j = 0; j < 8; ++j) {
            float s = opart[0][q * 64 + dd0 + j] + opart[1][q * 64 + dd0 + j]
                    + opart[2][q * 64 + dd0 + j] + opart[3][q * 64 + dd0 + j];
            o8[j] = f2bf(s * rc);
        }
        *reinterpret_cast<u16x8*>(o + ((size_t)(b * NN + qt + q) * HH + hh) * DHH + dd0) = o8;
    }
}

// ---------------- node logits ----------------
__global__ __launch_bounds__(256) void nodelogits_kernel(const float* __restrict__ h,
                                                         const float* __restrict__ nw,
                                                         const float* __restrict__ nb,
                                                         float* __restrict__ out)
{
    int row = blockIdx.x;
    int t = threadIdx.x;
    int kk = t & 15, seg = t >> 4;
    const float* hr = h + (size_t)row * DD;
    float acc = 0.f;
    #pragma unroll 8
    for (int d = seg * 32; d < seg * 32 + 32; ++d) acc += hr[d] * nw[d * KNN + kk];
    __shared__ float sm[16][17];
    sm[seg][kk] = acc;
    __syncthreads();
    if (t < KNN) {
        float s = 0.f;
        #pragma unroll
        for (int g2 = 0; g2 < 16; ++g2) s += sm[g2][t];
        out[(size_t)row * KNN + t] = s + nb[t];
    }
}

// ---------------- pair head: 32x32 tile, 2x2 micro, hard-sigmoid, d-split=2 ----------------
__global__ __launch_bounds__(256) void pair_kernel(
    const u16* __restrict__ pa8, const u16* __restrict__ pb8,
    const float* __restrict__ b1, const float* __restrict__ w2,
    float* __restrict__ etmp)
{
    const int jt = blockIdx.x * 32, it = blockIdx.y * 32;
    const int b = blockIdx.z >> 1, half = blockIdx.z & 1;
    const int t = threadIdx.x;
    const int j2 = t & 15, i2 = t >> 4;

    __shared__ float pas[32][132];
    __shared__ float pbs[32][132];
    __shared__ float4 w2s[128];

    float4 acc00 = {0,0,0,0}, acc01 = {0,0,0,0}, acc10 = {0,0,0,0}, acc11 = {0,0,0,0};

    for (int c2 = 0; c2 < 2; ++c2) {
        const int d0 = (half * 2 + c2) * 128;
        if (c2) __syncthreads();
        #pragma unroll
        for (int c = 0; c < 2; ++c) {
            int qd = c * 256 + t;
            int r = qd >> 4, part = (qd & 15) * 8;
            u16x8 av = *reinterpret_cast<const u16x8*>(pa8 + (size_t)(b * NN + it + r) * DD + d0 + part);
            u16x8 bv = *reinterpret_cast<const u16x8*>(pb8 + (size_t)(b * NN + jt + r) * DD + d0 + part);
            float4 b1a = *reinterpret_cast<const float4*>(b1 + d0 + part);
            float4 b1b = *reinterpret_cast<const float4*>(b1 + d0 + part + 4);
            *reinterpret_cast<float4*>(&pas[r][part]) =
                make_float4(bf2f(av[0]) + b1a.x, bf2f(av[1]) + b1a.y, bf2f(av[2]) + b1a.z, bf2f(av[3]) + b1a.w);
            *reinterpret_cast<float4*>(&pas[r][part + 4]) =
                make_float4(bf2f(av[4]) + b1b.x, bf2f(av[5]) + b1b.y, bf2f(av[6]) + b1b.z, bf2f(av[7]) + b1b.w);
            *reinterpret_cast<float4*>(&pbs[r][part]) =
                make_float4(bf2f(bv[0]), bf2f(bv[1]), bf2f(bv[2]), bf2f(bv[3]));
            *reinterpret_cast<float4*>(&pbs[r][part + 4]) =
                make_float4(bf2f(bv[4]), bf2f(bv[5]), bf2f(bv[6]), bf2f(bv[7]));
        }
        if (t < 128) w2s[t] = *reinterpret_cast<const float4*>(w2 + (size_t)(d0 + t) * KEE);
        __syncthreads();

        #pragma unroll 4
        for (int dq = 0; dq < 32; ++dq) {
            float4 paA = *reinterpret_cast<const float4*>(&pas[i2][dq * 4]);
            float4 paB = *reinterpret_cast<const float4*>(&pas[i2 + 16][dq * 4]);
            float4 pbA = *reinterpret_cast<const float4*>(&pbs[j2][dq * 4]);
            float4 pbB = *reinterpret_cast<const float4*>(&pbs[j2 + 16][dq * 4]);
            float4 w0 = w2s[dq * 4], w1 = w2s[dq * 4 + 1], w2v = w2s[dq * 4 + 2], w3 = w2s[dq * 4 + 3];

            #define HSILU(x) ((x) * __builtin_amdgcn_fmed3f(__builtin_fmaf((x), 0.25f, 0.5f), 0.f, 1.f))
            #define PAIR_STEP(ACC, PA, PB)                                                     \
            {                                                                                  \
                float s0 = HSILU(PA.x + PB.x), s1 = HSILU(PA.y + PB.y);                        \
                float s2 = HSILU(PA.z + PB.z), s3 = HSILU(PA.w + PB.w);                        \
                ACC.x += s0 * w0.x + s1 * w1.x + s2 * w2v.x + s3 * w3.x;                       \
                ACC.y += s0 * w0.y + s1 * w1.y + s2 * w2v.y + s3 * w3.y;                       \
                ACC.z += s0 * w0.z + s1 * w1.z + s2 * w2v.z + s3 * w3.z;                       \
                ACC.w += s0 * w0.w + s1 * w1.w + s2 * w2v.w + s3 * w3.w;                       \
            }
            PAIR_STEP(acc00, paA, pbA)
            PAIR_STEP(acc01, paA, pbB)
            PAIR_STEP(acc10, paB, pbA)
            PAIR_STEP(acc11, paB, pbB)
            #undef PAIR_STEP
            #undef HSILU
        }
    }

    float* ep = etmp + half * PSTRIDE;
    #define WRITE(ACC, I, J)                                                                   \
        *reinterpret_cast<float4*>(ep + (((size_t)(b * NN + (I)) * NN) + (J)) * KEE) =         \
            make_float4(ACC.x, ACC.y, ACC.z, ACC.w);
    WRITE(acc00, it + i2,      jt + j2)
    WRITE(acc01, it + i2,      jt + j2 + 16)
    WRITE(acc10, it + i2 + 16, jt + j2)
    WRITE(acc11, it + i2 + 16, jt + j2 + 16)
    #undef WRITE
}

// ---------------- symmetrize + diagonal + b2 (sums 2 d-split partials) ----------------
__global__ void symm_kernel(const float* __restrict__ et, const float* __restrict__ b2,
                            float* __restrict__ out)
{
    int idx = blockIdx.x * 256 + threadIdx.x; // B*N*N
    int j = idx & 255;
    int i = (idx >> 8) & 255;
    int b = idx >> 16;
    size_t fwd = (size_t)idx * KEE;
    size_t rev = (((size_t)b * NN + j) * NN + i) * KEE;
    float4 r4;
    if (i == j) {
        r4 = make_float4(1e9f, -1e9f, -1e9f, -1e9f);
    } else {
        float4 a0 = *reinterpret_cast<const float4*>(et + fwd);
        float4 a1 = *reinterpret_cast<const float4*>(et + PSTRIDE + fwd);
        float4 c0 = *reinterpret_cast<const float4*>(et + rev);
        float4 c1 = *reinterpret_cast<const float4*>(et + PSTRIDE + rev);
        r4 = make_float4(0.5f * (a0.x + a1.x + c0.x + c1.x) + b2[0],
                         0.5f * (a0.y + a1.y + c0.y + c1.y) + b2[1],
                         0.5f * (a0.z + a1.z + c0.z + c1.z) + b2[2],
                         0.5f * (a0.w + a1.w + c0.w + c1.w) + b2[3]);
    }
    *reinterpret_cast<float4*>(out + (size_t)BB * NN * KNN + fwd) = r4;
}

extern "C" void kernel_launch(void* const* d_in, const int* in_sizes, int n_in,
                              void* d_out, int out_size, void* d_ws, size_t ws_size,
                              hipStream_t stream)
{
    const int*   xn   = (const int*)d_in[0];
    const int*   xe   = (const int*)d_in[1];
    const int*   tt   = (const int*)d_in[2];
    const float* cemb = (const float*)d_in[3];
    const float* ne   = (const float*)d_in[4];
    const float* tw1  = (const float*)d_in[5];
    const float* tb1  = (const float*)d_in[6];
    const float* tw2  = (const float*)d_in[7];
    const float* tb2  = (const float*)d_in[8];
    const float* tab  = (const float*)d_in[9];
    const float* ln1g = (const float*)d_in[10];
    const float* ln1b = (const float*)d_in[11];
    const float* Wq   = (const float*)d_in[12];
    const float* Wk   = (const float*)d_in[13];
    const float* Wv   = (const float*)d_in[14];
    const float* Wo   = (const float*)d_in[15];
    const float* ln2g = (const float*)d_in[16];
    const float* ln2b = (const float*)d_in[17];
    const float* fw1  = (const float*)d_in[18];
    const float* fb1  = (const float*)d_in[19];
    const float* fw2  = (const float*)d_in[20];
    const float* fb2  = (const float*)d_in[21];
    const float* nw   = (const float*)d_in[22];
    const float* nb   = (const float*)d_in[23];
    const float* pw1  = (const float*)d_in[24];
    const float* pb1  = (const float*)d_in[25];
    const float* pw2  = (const float*)d_in[26];
    const float* pb2  = (const float*)d_in[27];
    float* out = (float*)d_out;

    char* wsb = (char*)d_ws;
    size_t off = 0;
    auto alloc = [&](size_t bytes) { char* p = wsb + off; off += (bytes + 255) & ~(size_t)255; return p; };

    float* temb = (float*)alloc(BB * DD * 4);
    float* h    = (float*)alloc((size_t)BB * NN * DD * 4);
    u16* hbf    = (u16*)alloc((size_t)BB * NN * DD * 2);
    float* statH = (float*)alloc((size_t)BB * NN * 32 * 4);
    u16* pa8    = (u16*)alloc((size_t)BB * NN * DD * 2);
    u16* pb8    = (u16*)alloc((size_t)BB * NN * DD * 2);
    u16* q8     = (u16*)alloc((size_t)BB * NN * DD * 2);
    u16* k8     = (u16*)alloc((size_t)BB * NN * DD * 2);
    u16* v8     = (u16*)alloc((size_t)BB * NN * DD * 2);
    u16* obf    = (u16*)alloc((size_t)BB * NN * DD * 2);
    u16* ff_bf  = (u16*)alloc((size_t)BB * NN * 4 * DD * 2);
    float* et   = (float*)alloc(2 * PSTRIDE * 4);
    u16* wqT    = (u16*)alloc((size_t)LL * DD * DD * 2);
    u16* wkT    = (u16*)alloc((size_t)LL * DD * DD * 2);
    u16* wvT    = (u16*)alloc((size_t)LL * DD * DD * 2);
    u16* woT    = (u16*)alloc((size_t)LL * DD * DD * 2);
    u16* fw1T   = (u16*)alloc((size_t)LL * DD * 4 * DD * 2);
    u16* fw2T   = (u16*)alloc((size_t)LL * DD * 4 * DD * 2);
    u16* pw1aT  = (u16*)alloc((size_t)DD * DD * 2);
    u16* pw1bT  = (u16*)alloc((size_t)DD * DD * 2);
    float* uq   = (float*)alloc((size_t)LL * DD * 4);
    float* vq   = (float*)alloc((size_t)LL * DD * 4);
    float* uk   = (float*)alloc((size_t)LL * DD * 4);
    float* vk   = (float*)alloc((size_t)LL * DD * 4);
    float* uvv  = (float*)alloc((size_t)LL * DD * 4);
    float* vvv  = (float*)alloc((size_t)LL * DD * 4);
    float* uf1  = (float*)alloc((size_t)LL * 4 * DD * 4);
    float* vf1  = (float*)alloc((size_t)LL * 4 * DD * 4);

    const int M = BB * NN;

    size_t foldBytes = (size_t)(6 * LL * DD + 2 * LL * 4 * DD) * 4 + 8 * 256;
    hipMemsetAsync(uq, 0, foldBytes, stream);

    CvtTab tb;
    tb.s[0] = { Wq,  wqT,  ln1g, ln1b, uq,  vq,  DD,     DD,     8,  8,  LL, 0    };
    tb.s[1] = { Wk,  wkT,  ln1g, ln1b, uk,  vk,  DD,     DD,     8,  8,  LL, 384  };
    tb.s[2] = { Wv,  wvT,  ln1g, ln1b, uvv, vvv, DD,     DD,     8,  8,  LL, 768  };
    tb.s[3] = { Wo,  woT,  nullptr, nullptr, nullptr, nullptr, DD, DD, 8, 8, LL, 1152 };
    tb.s[4] = { fw1, fw1T, ln2g, ln2b, uf1, vf1, DD,     4 * DD, 32, 8,  LL, 1536 };
    tb.s[5] = { fw2, fw2T, nullptr, nullptr, nullptr, nullptr, 4 * DD, DD, 8, 32, LL, 3072 };
    tb.s[6] = { pw1,                   pw1aT, nullptr, nullptr, nullptr, nullptr, DD, DD, 8, 8, 1, 4608 };
    tb.s[7] = { pw1 + (size_t)DD * DD, pw1bT, nullptr, nullptr, nullptr, nullptr, DD, DD, 8, 8, 1, 4672 };
    convert_all<<<4736, 256, 0, stream>>>(tb);

    temb_kernel<<<BB, DD, 0, stream>>>(tt, tw1, tb1, tw2, tb2, temb);
    inith_kernel<<<M, 256, 0, stream>>>(xn, ne, temb, cemb, h, hbf, statH);

    for (int l = 0; l < LL; ++l) {
        size_t wo512 = (size_t)l * DD * DD;
        size_t wo2k  = (size_t)l * DD * 4 * DD;
        // QKV: 64x128, KS=2, MODE1 (A = raw hbf, stats from statH), bf16 outputs
        gemm_mfma<2, 2, 2, 2, 1, false, false, false, true, false, false>
            <<<dim3(DD / 128, M / 64, 3), 512, 0, stream>>>(
            hbf, wqT + wo512, wkT + wo512, wvT + wo512,
            uq + l * DD, uk + l * DD, uvv + l * DD,
            vq + l * DD, vk + l * DD, vvv + l * DD,
            statH, nullptr, nullptr, q8, k8, v8, nullptr, nullptr, M, DD, DD);
        attn_kernel<<<dim3(8, HH, BB), 256, 0, stream>>>(q8, k8, v8, xe, tab, obf);
        // Wo: 32x64, KS=2, residual into h + hbf dual store + stat emit
        gemm_mfma<1, 2, 1, 2, 0, false, false, true, false, true, true>
            <<<dim3(DD / 64, M / 32, 1), 256, 0, stream>>>(
            obf, woT + wo512, nullptr, nullptr,
            nullptr, nullptr, nullptr, nullptr, nullptr, nullptr,
            nullptr, nullptr, h, h, nullptr, nullptr, hbf, statH, M, DD, DD);
        // FFN1: 64x128, KS=2, MODE1 (stats from statH), bias+silu, bf16 out
        gemm_mfma<2, 2, 2, 2, 1, true, true, false, true, false, false>
            <<<dim3(4 * DD / 128, M / 64, 1), 512, 0, stream>>>(
            hbf, fw1T + wo2k, nullptr, nullptr,
            uf1 + (size_t)l * 4 * DD, nullptr, nullptr,
            vf1 + (size_t)l * 4 * DD, nullptr, nullptr,
            statH, fb1 + (size_t)l * 4 * DD, nullptr, ff_bf, nullptr, nullptr, nullptr, nullptr,
            M, 4 * DD, DD);
        // FFN2: 32x64, KS=2, bias + residual + hbf dual store + stat emit
        gemm_mfma<1, 2, 1, 2, 0, true, false, true, false, true, true>
            <<<dim3(DD / 64, M / 32, 1), 256, 0, stream>>>(
            ff_bf, fw2T + wo2k, nullptr, nullptr,
            nullptr, nullptr, nullptr, nullptr, nullptr, nullptr,
            nullptr, fb2 + (size_t)l * DD, h, h, nullptr, nullptr, hbf, statH, M, DD, 4 * DD);
    }

    nodelogits_kernel<<<M, 256, 0, stream>>>(h, nw, nb, out);

    // pair projections from bf16 h
    gemm_mfma<1, 2, 1, 2, 0, false, false, false, true, false, false>
        <<<dim3(DD / 64, M / 32, 2), 256, 0, stream>>>(
        hbf, pw1aT, pw1bT, nullptr,
        nullptr, nullptr, nullptr, nullptr, nullptr, nullptr,
        nullptr, nullptr, nullptr, pa8, pb8, nullptr, nullptr, nullptr, M, DD, DD);

    pair_kernel<<<dim3(8, 8, BB * 2), 256, 0, stream>>>(pa8, pb8, pb1, pw2, et);
    symm_kernel<<<(BB * NN * NN) / 256, 256, 0, stream>>>(et, pb2, out);

    (void)in_sizes; (void)n_in; (void)out_size; (void)ws_size;
}

// Round 16
// 427.710 us; speedup vs baseline: 1.0565x; 1.0565x over previous
//
#include <hip/hip_runtime.h>
#include <math.h>

#define BB 4
#define NN 256
#define DD 512
#define HH 8
#define LL 6
#define TDIM 128
#define KNN 16
#define KEE 4
#define DHH 64
#define PSTRIDE ((size_t)BB * NN * NN * KEE)

typedef unsigned short u16;
typedef __bf16 bf16x8 __attribute__((ext_vector_type(8)));
typedef float f32x16 __attribute__((ext_vector_type(16)));
typedef u16 u16x8 __attribute__((ext_vector_type(8)));
typedef u16 u16x4 __attribute__((ext_vector_type(4)));
typedef unsigned int u32;

#define GLOBAL_AS(p) ((__attribute__((address_space(1))) void*)(p))
#define LDS_AS(p)    ((__attribute__((address_space(3))) void*)(p))

__device__ __forceinline__ u16 f2bf(float x) {
    unsigned u = __float_as_uint(x);
    u = (u + 0x7FFFu + ((u >> 16) & 1u)) >> 16;
    return (u16)u;
}
__device__ __forceinline__ float bf2f(u16 x) {
    return __uint_as_float(((unsigned)x) << 16);
}
__device__ __forceinline__ u32 cvtpk_bf16(float lo, float hi) {
    u32 r;
    asm("v_cvt_pk_bf16_f32 %0, %1, %2" : "=v"(r) : "v"(lo), "v"(hi));
    return r;
}

// ---------------- time embedding ----------------
__global__ void temb_kernel(const int* __restrict__ t_in, const float* __restrict__ w1,
                            const float* __restrict__ b1, const float* __restrict__ w2,
                            const float* __restrict__ b2, float* __restrict__ temb)
{
    int b = blockIdx.x;
    int t = threadIdx.x; // 512
    __shared__ float t0[TDIM];
    __shared__ float t1[DD];
    float tv = (float)t_in[b];
    if (t < TDIM) {
        int j = t & 63;
        float fr = expf(-logf(10000.f) * (float)j / 64.f);
        float ang = tv * fr;
        t0[t] = (t < 64) ? sinf(ang) : cosf(ang);
    }
    __syncthreads();
    float acc = b1[t];
    for (int k = 0; k < TDIM; ++k) acc += t0[k] * w1[k * DD + t];
    t1[t] = acc / (1.f + expf(-acc));
    __syncthreads();
    float acc2 = b2[t];
    for (int k = 0; k < DD; ++k) acc2 += t1[k] * w2[k * DD + t];
    temb[b * DD + t] = acc2;
}

// ---------------- h init ----------------
__global__ void inith_kernel(const int* __restrict__ xn, const float* __restrict__ ne,
                             const float* __restrict__ temb, const float* __restrict__ cemb,
                             float* __restrict__ h)
{
    int idx = blockIdx.x * 256 + threadIdx.x;
    int d = idx & (DD - 1);
    int bn = idx >> 9;
    int b = bn >> 8;
    h[idx] = ne[xn[bn] * DD + d] + temb[b * DD + d] + cemb[b * DD + d];
}

// ---------------- layernorm (fp32 in, bf16 out) ----------------
__global__ __launch_bounds__(256) void ln_kernel(const float* __restrict__ x,
                                                 const float* __restrict__ g,
                                                 const float* __restrict__ bta,
                                                 u16* __restrict__ y)
{
    int row = blockIdx.x;
    const float* xr = x + (size_t)row * DD;
    int t = threadIdx.x;
    float v0 = xr[t], v1 = xr[t + 256];
    float s = v0 + v1, sq = v0 * v0 + v1 * v1;
    #pragma unroll
    for (int o = 32; o; o >>= 1) { s += __shfl_down(s, o); sq += __shfl_down(sq, o); }
    __shared__ float ss[4], sqs[4];
    __shared__ float mean_s, rstd_s;
    int w = t >> 6, lane = t & 63;
    if (!lane) { ss[w] = s; sqs[w] = sq; }
    __syncthreads();
    if (t == 0) {
        float S = ss[0] + ss[1] + ss[2] + ss[3];
        float Q = sqs[0] + sqs[1] + sqs[2] + sqs[3];
        float m = S / DD;
        float var = Q / DD - m * m;
        mean_s = m; rstd_s = rsqrtf(var + 1e-5f);
    }
    __syncthreads();
    float m = mean_s, r = rstd_s;
    y[(size_t)row * DD + t]       = f2bf((v0 - m) * r * g[t] + bta[t]);
    y[(size_t)row * DD + t + 256] = f2bf((v1 - m) * r * g[t + 256] + bta[t + 256]);
}

// ---------------- merged weight convert+transpose: [K][N] fp32 -> [N][K] bf16 ----------------
struct CvtSeg { const float* src; u16* dst; int K, N, tx, ty, nl, base; };
struct CvtTab { CvtSeg s[8]; };

__global__ __launch_bounds__(256) void convert_all(CvtTab tab)
{
    const int tile = blockIdx.x;
    int si = 0;
    #pragma unroll
    for (int s2 = 1; s2 < 8; ++s2) if (tile >= tab.s[s2].base) si = s2;
    const CvtSeg sg = tab.s[si];
    int local = tile - sg.base;
    int per = sg.tx * sg.ty;
    int lay = local / per;
    int rem = local - lay * per;
    int bx = rem % sg.tx, by = rem / sg.tx;
    const int kb = by * 64, nb = bx * 64;
    const size_t zoff = (size_t)lay * sg.K * sg.N;
    const int K = sg.K, N = sg.N;

    __shared__ float s[64][65];
    int t = threadIdx.x;
    int r0 = t >> 4, c0 = (t & 15) * 4;
    #pragma unroll
    for (int i = 0; i < 4; ++i) {
        int row = i * 16 + r0;
        float4 v = *reinterpret_cast<const float4*>(sg.src + zoff + (size_t)(kb + row) * N + nb + c0);
        s[row][c0] = v.x; s[row][c0 + 1] = v.y; s[row][c0 + 2] = v.z; s[row][c0 + 3] = v.w;
    }
    __syncthreads();
    #pragma unroll
    for (int i = 0; i < 4; ++i) {
        int n = i * 16 + r0;
        ushort4 o;
        o.x = f2bf(s[c0 + 0][n]); o.y = f2bf(s[c0 + 1][n]);
        o.z = f2bf(s[c0 + 2][n]); o.w = f2bf(s[c0 + 3][n]);
        *reinterpret_cast<ushort4*>(sg.dst + zoff + (size_t)(nb + n) * K + kb + c0) = o;
    }
}

// ---------------- MFMA GEMM with in-block split-K (KS groups), dbuf ----------------
template<int WM, int WN, int NR, int KS, bool BIAS, bool SILU, bool RES, bool OBF, bool HBF>
__global__ __launch_bounds__(WM * WN * 64 * KS) void gemm_mfma(
    const u16* __restrict__ A,
    const u16* __restrict__ B0, const u16* __restrict__ B1, const u16* __restrict__ B2,
    const float* __restrict__ bias, const float* res,
    void* O0, void* O1, void* O2, u16* hbf,
    int M, int N, int K)
{
    constexpr int BM = WM * 32, BN = WN * NR * 32;
    constexpr int GW = WM * WN;
    constexpr int TH = GW * 64;
    constexpr int ABYTES = BM * 128;
    constexpr int BBYTES = BN * 128;
    constexpr int A16 = ABYTES / 16;
    constexpr int B16 = BBYTES / 16;
    __shared__ char smem[KS * 2 * (ABYTES + BBYTES)];

    const u16* Bm = B0; void* O = O0;
    if (blockIdx.z == 1) { Bm = B1; O = O1; }
    else if (blockIdx.z == 2) { Bm = B2; O = O2; }

    const int t = threadIdx.x;
    const int l = t & 63;
    const int w = t >> 6;
    const int ks = w / GW;
    const int wsub = w - ks * GW;
    const int tl = wsub * 64 + l;
    const int lo = l & 31, hi = l >> 5;
    const int wm = wsub / WN, wn = wsub % WN;
    const int row0 = blockIdx.y * BM;
    const int col0 = blockIdx.x * BN;
    const int NK = K >> 6;
    const int NKh = NK / KS;

    char* gbase = smem + ks * 2 * (ABYTES + BBYTES);

    int aoff[4];
    int boff[NR][4];
    #pragma unroll
    for (int kc = 0; kc < 4; ++kc) {
        int slot = (kc * 2 + hi) ^ (lo & 7);
        aoff[kc] = (wm * 32 + lo) * 128 + slot * 16;
        #pragma unroll
        for (int nr = 0; nr < NR; ++nr)
            boff[nr][kc] = (wn * NR * 32 + nr * 32 + lo) * 128 + slot * 16;
    }

    auto stage = [&](int buf, int kt) {
        const int k0 = kt * 64;
        char* base = gbase + buf * (ABYTES + BBYTES);
        #pragma unroll
        for (int idx = tl; idx < A16; idx += TH) {
            int r = idx >> 3, s = idx & 7;
            int ss = s ^ (r & 7);
            const u16* g = A + (size_t)(row0 + r) * K + k0 + ss * 8;
            __builtin_amdgcn_global_load_lds(GLOBAL_AS(g), LDS_AS(base + (idx - l) * 16), 16, 0, 0);
        }
        #pragma unroll
        for (int idx = tl; idx < B16; idx += TH) {
            int r = idx >> 3, s = idx & 7;
            int ss = s ^ (r & 7);
            const u16* g = Bm + (size_t)(col0 + r) * K + k0 + ss * 8;
            __builtin_amdgcn_global_load_lds(GLOBAL_AS(g), LDS_AS(base + ABYTES + (idx - l) * 16), 16, 0, 0);
        }
    };

    f32x16 acc[NR];
    #pragma unroll
    for (int nr = 0; nr < NR; ++nr)
        #pragma unroll
        for (int i = 0; i < 16; ++i) acc[nr][i] = 0.f;

    stage(0, ks * NKh);
    __syncthreads();
    int cur = 0;
    for (int kk = 0; kk < NKh; ++kk) {
        if (kk + 1 < NKh) stage(cur ^ 1, ks * NKh + kk + 1);
        const char* base = gbase + cur * (ABYTES + BBYTES);
        #pragma unroll
        for (int kc = 0; kc < 4; ++kc) {
            bf16x8 av = *reinterpret_cast<const bf16x8*>(base + aoff[kc]);
            #pragma unroll
            for (int nr = 0; nr < NR; ++nr) {
                bf16x8 bb = *reinterpret_cast<const bf16x8*>(base + ABYTES + boff[nr][kc]);
                acc[nr] = __builtin_amdgcn_mfma_f32_32x32x16_bf16(av, bb, acc[nr], 0, 0, 0);
            }
        }
        __syncthreads();
        cur ^= 1;
    }

    if (KS > 1) {
        float* exch = (float*)smem;
        if (ks > 0) {
            #pragma unroll
            for (int nr = 0; nr < NR; ++nr)
                #pragma unroll
                for (int r = 0; r < 16; ++r)
                    exch[(((ks - 1) * NR + nr) * 16 + r) * TH + tl] = acc[nr][r];
        }
        __syncthreads();
        if (ks != 0) return;
        #pragma unroll
        for (int g2 = 1; g2 < KS; ++g2)
            #pragma unroll
            for (int nr = 0; nr < NR; ++nr)
                #pragma unroll
                for (int r = 0; r < 16; ++r)
                    acc[nr][r] += exch[(((g2 - 1) * NR + nr) * 16 + r) * TH + tl];
    }

    #pragma unroll
    for (int nr = 0; nr < NR; ++nr) {
        int col = col0 + wn * NR * 32 + nr * 32 + lo;
        float bs = BIAS ? bias[col] : 0.f;
        #pragma unroll
        for (int r = 0; r < 16; ++r) {
            int row = row0 + wm * 32 + (r & 3) + 8 * (r >> 2) + 4 * hi;
            float v = acc[nr][r] + bs;
            if (SILU) v = v / (1.f + __expf(-v));
            size_t o = (size_t)row * N + col;
            if (RES) v += res[o];
            if (OBF) ((u16*)O)[o] = f2bf(v);
            else { ((float*)O)[o] = v; if (HBF) hbf[o] = f2bf(v); }
        }
    }
}

// ---------------- attention v4: full MFMA (S^T = K@Q^T, in-reg softmax, P@V) ----------------
// grid (8 qtiles of 32, H, B), 256 thr = 4 waves. Wave w owns keys 64w..64w+63.
__global__ __launch_bounds__(256) void attn_kernel(
    const u16* __restrict__ q8, const u16* __restrict__ k8, const u16* __restrict__ v8,
    const int* __restrict__ xe, const float* __restrict__ tab, u16* __restrict__ o)
{
    const int qt = blockIdx.x * 32, hh = blockIdx.y, b = blockIdx.z;
    const int t = threadIdx.x;
    const int l = t & 63, w = t >> 6;
    const int lo = l & 31, hi = l >> 5;

    __shared__ u16 Ks[NN * 64];        // 32KB, rows 128B, 8 slots swizzled ^(key&7)
    __shared__ u16 Qs[32 * 64];        // 4KB,  rows 128B, swizzled ^(q&7)
    __shared__ u16 Vt[64 * NN];        // 32KB, V^T rows 512B (256 keys), 32 slots swz ^(d&31)
    __shared__ float opart[4][32 * 64];// 32KB
    __shared__ float sums[4][32];
    __shared__ float tabs[KEE * HH];

    // ---- stage K (DMA, pre-swizzled source) ----
    #pragma unroll
    for (int c = 0; c < 8; ++c) {
        int idx = c * 256 + t;
        int r = idx >> 3, s = idx & 7;
        int ss = s ^ (r & 7);
        const u16* g = k8 + ((size_t)(b * NN + r) * HH + hh) * DHH + ss * 8;
        __builtin_amdgcn_global_load_lds(GLOBAL_AS(g), LDS_AS((char*)Ks + (idx - l) * 16), 16, 0, 0);
    }
    // ---- stage Q (DMA) ----
    {
        int r = t >> 3, s = t & 7;
        int ss = s ^ (r & 7);
        const u16* g = q8 + ((size_t)(b * NN + qt + r) * HH + hh) * DHH + ss * 8;
        __builtin_amdgcn_global_load_lds(GLOBAL_AS(g), LDS_AS((char*)Qs + (t - l) * 16), 16, 0, 0);
    }
    if (t < KEE * HH) tabs[t] = tab[t];

    // ---- stage V^T via in-register 8x8 transpose ----
    {
        const int d0 = (t & 7) * 8, k0 = (t >> 3) * 8;
        u16x8 va[8];
        #pragma unroll
        for (int i = 0; i < 8; ++i)
            va[i] = *reinterpret_cast<const u16x8*>(v8 + ((size_t)(b * NN + k0 + i) * HH + hh) * DHH + d0);
        #pragma unroll
        for (int j = 0; j < 8; ++j) {
            u16x8 tj;
            #pragma unroll
            for (int i = 0; i < 8; ++i) tj[i] = va[i][j];
            int d = d0 + j;
            int slot = (k0 >> 3) ^ (d & 31);
            *reinterpret_cast<u16x8*>(&Vt[d * 256 + slot * 8]) = tj;
        }
    }
    __syncthreads();

    // ---- S^T = K @ Q^T : wave w covers key tiles 2w, 2w+1 ----
    f32x16 acc[2];
    #pragma unroll
    for (int i = 0; i < 2; ++i)
        #pragma unroll
        for (int r = 0; r < 16; ++r) acc[i][r] = 0.f;

    #pragma unroll
    for (int kc = 0; kc < 4; ++kc) {
        int qslot = (kc * 2 + hi) ^ (lo & 7);
        bf16x8 bq = *reinterpret_cast<const bf16x8*>((char*)Qs + lo * 128 + qslot * 16);
        #pragma unroll
        for (int ktl = 0; ktl < 2; ++ktl) {
            int key = (2 * w + ktl) * 32 + lo;
            int kslot = (kc * 2 + hi) ^ (key & 7);
            bf16x8 ak = *reinterpret_cast<const bf16x8*>((char*)Ks + key * 128 + kslot * 16);
            acc[ktl] = __builtin_amdgcn_mfma_f32_32x32x16_bf16(ak, bq, acc[ktl], 0, 0, 0);
        }
    }

    // ---- bias + exp + partial sums (q = lo is lane-local) ----
    const int qrow = qt + lo;
    const int* xerow = xe + (size_t)(b * NN + qrow) * NN;
    float psum = 0.f;
    #pragma unroll
    for (int ktl = 0; ktl < 2; ++ktl) {
        #pragma unroll
        for (int r = 0; r < 16; ++r) {
            int key = w * 64 + ktl * 32 + (r & 3) + 8 * (r >> 2) + 4 * hi;
            int e = xerow[key];
            float p = __expf(acc[ktl][r] * 0.125f + tabs[e * HH + hh]);
            acc[ktl][r] = p;
            psum += p;
        }
    }
    psum += __shfl_xor(psum, 32);
    if (hi == 0) sums[w][lo] = psum;

    // ---- AV: P (in-reg, cvtpk + shfl assemble) @ V (from Vt) ----
    f32x16 oacc[2];
    #pragma unroll
    for (int i = 0; i < 2; ++i)
        #pragma unroll
        for (int r = 0; r < 16; ++r) oacc[i][r] = 0.f;

    #pragma unroll
    for (int kc = 0; kc < 4; ++kc) {
        const int ai = kc >> 1;
        const int s0 = 8 * (kc & 1);
        u32 W0p = cvtpk_bf16(acc[ai][s0 + 0], acc[ai][s0 + 1]);
        u32 W1p = cvtpk_bf16(acc[ai][s0 + 2], acc[ai][s0 + 3]);
        u32 X0p = cvtpk_bf16(acc[ai][s0 + 4], acc[ai][s0 + 5]);
        u32 X1p = cvtpk_bf16(acc[ai][s0 + 6], acc[ai][s0 + 7]);
        u32 z0 = hi ? W0p : X0p;
        u32 z1 = hi ? W1p : X1p;
        u32 r0 = __shfl_xor((int)z0, 32);
        u32 r1 = __shfl_xor((int)z1, 32);
        u32 F[4];
        F[0] = hi ? r0 : W0p;
        F[1] = hi ? r1 : W1p;
        F[2] = hi ? X0p : r0;
        F[3] = hi ? X1p : r1;
        bf16x8 pf = *reinterpret_cast<const bf16x8*>(F);
        #pragma unroll
        for (int nt = 0; nt < 2; ++nt) {
            int d = nt * 32 + lo;
            int slot = (8 * w + kc * 2 + hi) ^ (d & 31);
            bf16x8 vf = *reinterpret_cast<const bf16x8*>(&Vt[d * 256 + slot * 8]);
            oacc[nt] = __builtin_amdgcn_mfma_f32_32x32x16_bf16(pf, vf, oacc[nt], 0, 0, 0);
        }
    }

    // ---- write per-wave partial O ----
    #pragma unroll
    for (int nt = 0; nt < 2; ++nt)
        #pragma unroll
        for (int r = 0; r < 16; ++r) {
            int q = (r & 3) + 8 * (r >> 2) + 4 * hi;
            opart[w][q * 64 + nt * 32 + lo] = oacc[nt][r];
        }
    __syncthreads();

    // ---- reduce, normalize, store ----
    {
        const int q = t >> 3, dd0 = (t & 7) * 8;
        float denom = sums[0][q] + sums[1][q] + sums[2][q] + sums[3][q];
        float rc = __builtin_amdgcn_rcpf(denom);
        u16x8 o8;
        #pragma unroll
        for (int j = 0; j < 8; ++j) {
            float s = opart[0][q * 64 + dd0 + j] + opart[1][q * 64 + dd0 + j]
                    + opart[2][q * 64 + dd0 + j] + opart[3][q * 64 + dd0 + j];
            o8[j] = f2bf(s * rc);
        }
        *reinterpret_cast<u16x8*>(o + ((size_t)(b * NN + qt + q) * HH + hh) * DHH + dd0) = o8;
    }
}

// ---------------- node logits ----------------
__global__ __launch_bounds__(256) void nodelogits_kernel(const float* __restrict__ h,
                                                         const float* __restrict__ nw,
                                                         const float* __restrict__ nb,
                                                         float* __restrict__ out)
{
    int row = blockIdx.x;
    int t = threadIdx.x;
    int kk = t & 15, seg = t >> 4;
    const float* hr = h + (size_t)row * DD;
    float acc = 0.f;
    #pragma unroll 8
    for (int d = seg * 32; d < seg * 32 + 32; ++d) acc += hr[d] * nw[d * KNN + kk];
    __shared__ float sm[16][17];
    sm[seg][kk] = acc;
    __syncthreads();
    if (t < KNN) {
        float s = 0.f;
        #pragma unroll
        for (int g2 = 0; g2 < 16; ++g2) s += sm[g2][t];
        out[(size_t)row * KNN + t] = s + nb[t];
    }
}

// ---------------- pair head: 32x32 tile, 2x2 micro, hard-sigmoid, d-split=2 ----------------
__global__ __launch_bounds__(256) void pair_kernel(
    const u16* __restrict__ pa8, const u16* __restrict__ pb8,
    const float* __restrict__ b1, const float* __restrict__ w2,
    float* __restrict__ etmp)
{
    const int jt = blockIdx.x * 32, it = blockIdx.y * 32;
    const int b = blockIdx.z >> 1, half = blockIdx.z & 1;
    const int t = threadIdx.x;
    const int j2 = t & 15, i2 = t >> 4;

    __shared__ float pas[32][132];
    __shared__ float pbs[32][132];
    __shared__ float4 w2s[128];

    float4 acc00 = {0,0,0,0}, acc01 = {0,0,0,0}, acc10 = {0,0,0,0}, acc11 = {0,0,0,0};

    for (int c2 = 0; c2 < 2; ++c2) {
        const int d0 = (half * 2 + c2) * 128;
        if (c2) __syncthreads();
        #pragma unroll
        for (int c = 0; c < 2; ++c) {
            int qd = c * 256 + t;
            int r = qd >> 4, part = (qd & 15) * 8;
            u16x8 av = *reinterpret_cast<const u16x8*>(pa8 + (size_t)(b * NN + it + r) * DD + d0 + part);
            u16x8 bv = *reinterpret_cast<const u16x8*>(pb8 + (size_t)(b * NN + jt + r) * DD + d0 + part);
            float4 b1a = *reinterpret_cast<const float4*>(b1 + d0 + part);
            float4 b1b = *reinterpret_cast<const float4*>(b1 + d0 + part + 4);
            *reinterpret_cast<float4*>(&pas[r][part]) =
                make_float4(bf2f(av[0]) + b1a.x, bf2f(av[1]) + b1a.y, bf2f(av[2]) + b1a.z, bf2f(av[3]) + b1a.w);
            *reinterpret_cast<float4*>(&pas[r][part + 4]) =
                make_float4(bf2f(av[4]) + b1b.x, bf2f(av[5]) + b1b.y, bf2f(av[6]) + b1b.z, bf2f(av[7]) + b1b.w);
            *reinterpret_cast<float4*>(&pbs[r][part]) =
                make_float4(bf2f(bv[0]), bf2f(bv[1]), bf2f(bv[2]), bf2f(bv[3]));
            *reinterpret_cast<float4*>(&pbs[r][part + 4]) =
                make_float4(bf2f(bv[4]), bf2f(bv[5]), bf2f(bv[6]), bf2f(bv[7]));
        }
        if (t < 128) w2s[t] = *reinterpret_cast<const float4*>(w2 + (size_t)(d0 + t) * KEE);
        __syncthreads();

        #pragma unroll 4
        for (int dq = 0; dq < 32; ++dq) {
            float4 paA = *reinterpret_cast<const float4*>(&pas[i2][dq * 4]);
            float4 paB = *reinterpret_cast<const float4*>(&pas[i2 + 16][dq * 4]);
            float4 pbA = *reinterpret_cast<const float4*>(&pbs[j2][dq * 4]);
            float4 pbB = *reinterpret_cast<const float4*>(&pbs[j2 + 16][dq * 4]);
            float4 w0 = w2s[dq * 4], w1 = w2s[dq * 4 + 1], w2v = w2s[dq * 4 + 2], w3 = w2s[dq * 4 + 3];

            #define HSILU(x) ((x) * __builtin_amdgcn_fmed3f(__builtin_fmaf((x), 0.25f, 0.5f), 0.f, 1.f))
            #define PAIR_STEP(ACC, PA, PB)                                                     \
            {                                                                                  \
                float s0 = HSILU(PA.x + PB.x), s1 = HSILU(PA.y + PB.y);                        \
                float s2 = HSILU(PA.z + PB.z), s3 = HSILU(PA.w + PB.w);                        \
                ACC.x += s0 * w0.x + s1 * w1.x + s2 * w2v.x + s3 * w3.x;                       \
                ACC.y += s0 * w0.y + s1 * w1.y + s2 * w2v.y + s3 * w3.y;                       \
                ACC.z += s0 * w0.z + s1 * w1.z + s2 * w2v.z + s3 * w3.z;                       \
                ACC.w += s0 * w0.w + s1 * w1.w + s2 * w2v.w + s3 * w3.w;                       \
            }
            PAIR_STEP(acc00, paA, pbA)
            PAIR_STEP(acc01, paA, pbB)
            PAIR_STEP(acc10, paB, pbA)
            PAIR_STEP(acc11, paB, pbB)
            #undef PAIR_STEP
            #undef HSILU
        }
    }

    float* ep = etmp + half * PSTRIDE;
    #define WRITE(ACC, I, J)                                                                   \
        *reinterpret_cast<float4*>(ep + (((size_t)(b * NN + (I)) * NN) + (J)) * KEE) =         \
            make_float4(ACC.x, ACC.y, ACC.z, ACC.w);
    WRITE(acc00, it + i2,      jt + j2)
    WRITE(acc01, it + i2,      jt + j2 + 16)
    WRITE(acc10, it + i2 + 16, jt + j2)
    WRITE(acc11, it + i2 + 16, jt + j2 + 16)
    #undef WRITE
}

// ---------------- symmetrize + diagonal + b2 (sums 2 d-split partials) ----------------
__global__ void symm_kernel(const float* __restrict__ et, const float* __restrict__ b2,
                            float* __restrict__ out)
{
    int idx = blockIdx.x * 256 + threadIdx.x; // B*N*N
    int j = idx & 255;
    int i = (idx >> 8) & 255;
    int b = idx >> 16;
    size_t fwd = (size_t)idx * KEE;
    size_t rev = (((size_t)b * NN + j) * NN + i) * KEE;
    float4 r4;
    if (i == j) {
        r4 = make_float4(1e9f, -1e9f, -1e9f, -1e9f);
    } else {
        float4 a0 = *reinterpret_cast<const float4*>(et + fwd);
        float4 a1 = *reinterpret_cast<const float4*>(et + PSTRIDE + fwd);
        float4 c0 = *reinterpret_cast<const float4*>(et + rev);
        float4 c1 = *reinterpret_cast<const float4*>(et + PSTRIDE + rev);
        r4 = make_float4(0.5f * (a0.x + a1.x + c0.x + c1.x) + b2[0],
                         0.5f * (a0.y + a1.y + c0.y + c1.y) + b2[1],
                         0.5f * (a0.z + a1.z + c0.z + c1.z) + b2[2],
                         0.5f * (a0.w + a1.w + c0.w + c1.w) + b2[3]);
    }
    *reinterpret_cast<float4*>(out + (size_t)BB * NN * KNN + fwd) = r4;
}

extern "C" void kernel_launch(void* const* d_in, const int* in_sizes, int n_in,
                              void* d_out, int out_size, void* d_ws, size_t ws_size,
                              hipStream_t stream)
{
    const int*   xn   = (const int*)d_in[0];
    const int*   xe   = (const int*)d_in[1];
    const int*   tt   = (const int*)d_in[2];
    const float* cemb = (const float*)d_in[3];
    const float* ne   = (const float*)d_in[4];
    const float* tw1  = (const float*)d_in[5];
    const float* tb1  = (const float*)d_in[6];
    const float* tw2  = (const float*)d_in[7];
    const float* tb2  = (const float*)d_in[8];
    const float* tab  = (const float*)d_in[9];
    const float* ln1g = (const float*)d_in[10];
    const float* ln1b = (const float*)d_in[11];
    const float* Wq   = (const float*)d_in[12];
    const float* Wk   = (const float*)d_in[13];
    const float* Wv   = (const float*)d_in[14];
    const float* Wo   = (const float*)d_in[15];
    const float* ln2g = (const float*)d_in[16];
    const float* ln2b = (const float*)d_in[17];
    const float* fw1  = (const float*)d_in[18];
    const float* fb1  = (const float*)d_in[19];
    const float* fw2  = (const float*)d_in[20];
    const float* fb2  = (const float*)d_in[21];
    const float* nw   = (const float*)d_in[22];
    const float* nb   = (const float*)d_in[23];
    const float* pw1  = (const float*)d_in[24];
    const float* pb1  = (const float*)d_in[25];
    const float* pw2  = (const float*)d_in[26];
    const float* pb2  = (const float*)d_in[27];
    float* out = (float*)d_out;

    char* wsb = (char*)d_ws;
    size_t off = 0;
    auto alloc = [&](size_t bytes) { char* p = wsb + off; off += (bytes + 255) & ~(size_t)255; return p; };

    float* temb = (float*)alloc(BB * DD * 4);
    float* h    = (float*)alloc((size_t)BB * NN * DD * 4);
    u16* hbf    = (u16*)alloc((size_t)BB * NN * DD * 2);
    u16* pa8    = (u16*)alloc((size_t)BB * NN * DD * 2);
    u16* pb8    = (u16*)alloc((size_t)BB * NN * DD * 2);
    u16* q8     = (u16*)alloc((size_t)BB * NN * DD * 2);
    u16* k8     = (u16*)alloc((size_t)BB * NN * DD * 2);
    u16* v8     = (u16*)alloc((size_t)BB * NN * DD * 2);
    u16* hn_bf  = (u16*)alloc((size_t)BB * NN * DD * 2);
    u16* obf    = (u16*)alloc((size_t)BB * NN * DD * 2);
    u16* ff_bf  = (u16*)alloc((size_t)BB * NN * 4 * DD * 2);
    float* et   = (float*)alloc(2 * PSTRIDE * 4);
    u16* wqT    = (u16*)alloc((size_t)LL * DD * DD * 2);
    u16* wkT    = (u16*)alloc((size_t)LL * DD * DD * 2);
    u16* wvT    = (u16*)alloc((size_t)LL * DD * DD * 2);
    u16* woT    = (u16*)alloc((size_t)LL * DD * DD * 2);
    u16* fw1T   = (u16*)alloc((size_t)LL * DD * 4 * DD * 2);
    u16* fw2T   = (u16*)alloc((size_t)LL * DD * 4 * DD * 2);
    u16* pw1aT  = (u16*)alloc((size_t)DD * DD * 2);
    u16* pw1bT  = (u16*)alloc((size_t)DD * DD * 2);

    const int M = BB * NN;

    CvtTab tb;
    tb.s[0] = { Wq,  wqT,  DD,     DD,     8,  8,  LL, 0    };
    tb.s[1] = { Wk,  wkT,  DD,     DD,     8,  8,  LL, 384  };
    tb.s[2] = { Wv,  wvT,  DD,     DD,     8,  8,  LL, 768  };
    tb.s[3] = { Wo,  woT,  DD,     DD,     8,  8,  LL, 1152 };
    tb.s[4] = { fw1, fw1T, DD,     4 * DD, 32, 8,  LL, 1536 };
    tb.s[5] = { fw2, fw2T, 4 * DD, DD,     8,  32, LL, 3072 };
    tb.s[6] = { pw1,                   pw1aT, DD, DD, 8, 8, 1, 4608 };
    tb.s[7] = { pw1 + (size_t)DD * DD, pw1bT, DD, DD, 8, 8, 1, 4672 };
    convert_all<<<4736, 256, 0, stream>>>(tb);

    temb_kernel<<<BB, DD, 0, stream>>>(tt, tw1, tb1, tw2, tb2, temb);
    inith_kernel<<<(BB * NN * DD) / 256, 256, 0, stream>>>(xn, ne, temb, cemb, h);

    for (int l = 0; l < LL; ++l) {
        size_t wo512 = (size_t)l * DD * DD;
        size_t wo2k  = (size_t)l * DD * 4 * DD;
        ln_kernel<<<M, 256, 0, stream>>>(h, ln1g + l * DD, ln1b + l * DD, hn_bf);
        // QKV: 64x128 tile, KS=2 (512 thr), bf16 outputs
        gemm_mfma<2, 2, 2, 2, false, false, false, true, false><<<dim3(DD / 128, M / 64, 3), 512, 0, stream>>>(
            hn_bf, wqT + wo512, wkT + wo512, wvT + wo512, nullptr, nullptr,
            q8, k8, v8, nullptr, M, DD, DD);
        attn_kernel<<<dim3(8, HH, BB), 256, 0, stream>>>(q8, k8, v8, xe, tab, obf);
        // Wo: 32x64 tile, KS=2, residual into h
        gemm_mfma<1, 2, 1, 2, false, false, true, false, false><<<dim3(DD / 64, M / 32, 1), 256, 0, stream>>>(
            obf, woT + wo512, nullptr, nullptr, nullptr, h,
            h, nullptr, nullptr, nullptr, M, DD, DD);
        ln_kernel<<<M, 256, 0, stream>>>(h, ln2g + l * DD, ln2b + l * DD, hn_bf);
        // FFN1: 64x128 tile, KS=2, bias+silu, bf16 out
        gemm_mfma<2, 2, 2, 2, true, true, false, true, false><<<dim3(4 * DD / 128, M / 64, 1), 512, 0, stream>>>(
            hn_bf, fw1T + wo2k, nullptr, nullptr, fb1 + (size_t)l * 4 * DD, nullptr,
            ff_bf, nullptr, nullptr, nullptr, M, 4 * DD, DD);
        // FFN2: 32x64 tile, KS=2, bias + residual; last layer dual-stores bf16 h
        if (l == LL - 1)
            gemm_mfma<1, 2, 1, 2, true, false, true, false, true><<<dim3(DD / 64, M / 32, 1), 256, 0, stream>>>(
                ff_bf, fw2T + wo2k, nullptr, nullptr, fb2 + (size_t)l * DD, h,
                h, nullptr, nullptr, hbf, M, DD, 4 * DD);
        else
            gemm_mfma<1, 2, 1, 2, true, false, true, false, false><<<dim3(DD / 64, M / 32, 1), 256, 0, stream>>>(
                ff_bf, fw2T + wo2k, nullptr, nullptr, fb2 + (size_t)l * DD, h,
                h, nullptr, nullptr, nullptr, M, DD, 4 * DD);
    }

    nodelogits_kernel<<<M, 256, 0, stream>>>(h, nw, nb, out);

    // pair projections from bf16 h
    gemm_mfma<1, 2, 1, 2, false, false, false, true, false><<<dim3(DD / 64, M / 32, 2), 256, 0, stream>>>(
        hbf, pw1aT, pw1bT, nullptr, nullptr, nullptr,
        pa8, pb8, nullptr, nullptr, M, DD, DD);

    pair_kernel<<<dim3(8, 8, BB * 2), 256, 0, stream>>>(pa8, pb8, pb1, pw2, et);
    symm_kernel<<<(BB * NN * NN) / 256, 256, 0, stream>>>(et, pb2, out);

    (void)in_sizes; (void)n_in; (void)out_size; (void)ws_size;
}